// Round 5
// baseline (877.568 us; speedup 1.0000x reference)
//
#include <hip/hip_runtime.h>

#define N_NODES 50000
#define M_EDGES 800000
#define RP 50048  // padded row count for matrix buffers

typedef __bf16 bf16x8 __attribute__((ext_vector_type(8)));
typedef __bf16 bf16x4 __attribute__((ext_vector_type(4)));
typedef float  f32x4  __attribute__((ext_vector_type(4)));

static __device__ __forceinline__ unsigned enc_ord(float f) {
    unsigned b = __float_as_uint(f);
    return (b & 0x80000000u) ? ~b : (b | 0x80000000u);
}
static __device__ __forceinline__ float dec_ord(unsigned u) {
    unsigned b = (u & 0x80000000u) ? (u ^ 0x80000000u) : ~u;
    return __uint_as_float(b);
}
// bf16 pair packed in a uint: lo = bits[15:0], hi = bits[31:16]
static __device__ __forceinline__ float bflo(unsigned u) { return __uint_as_float(u << 16); }
static __device__ __forceinline__ float bfhi(unsigned u) { return __uint_as_float(u & 0xffff0000u); }

// async 16B global -> LDS DMA (vmcnt op; LDS dest = wave-uniform base + lane*16)
static __device__ __forceinline__ void gload16(const void* g, void* l) {
    __builtin_amdgcn_global_load_lds(
        (const __attribute__((address_space(1))) void*)g,
        (__attribute__((address_space(3))) void*)l, 16, 0, 0);
}

__global__ void init_kernel(int* counts, int* cursor, unsigned* gmax) {
    int t = blockIdx.x * blockDim.x + threadIdx.x;
    if (t < N_NODES) { counts[t] = 0; cursor[t] = 0; }
    if (t == 0) *gmax = 0u;
}

__global__ void wsplit_kernel(const float* __restrict__ W,
                              __bf16* __restrict__ th, __bf16* __restrict__ tl) {
    int t = blockIdx.x * 256 + threadIdx.x;
    int n = t >> 8, k = t & 255;
    float v = W[(size_t)k * 256 + n];
    __bf16 h = (__bf16)v;
    th[t] = h;
    tl[t] = (__bf16)(v - (float)h);
}

// ---- one-pass fp32 -> split-bf16 (h + l) for GEMM A operands.
__global__ void xsplit_kernel(const float* __restrict__ X,
                              __bf16* __restrict__ xh, __bf16* __restrict__ xl) {
    size_t i = ((size_t)blockIdx.x * 256 + threadIdx.x) * 4;
    if (i >= (size_t)N_NODES * 256) return;
    float4 v = *(const float4*)(X + i);
    bf16x4 hh, ll;
    hh[0] = (__bf16)v.x; ll[0] = (__bf16)(v.x - (float)hh[0]);
    hh[1] = (__bf16)v.y; ll[1] = (__bf16)(v.y - (float)hh[1]);
    hh[2] = (__bf16)v.z; ll[2] = (__bf16)(v.z - (float)hh[2]);
    hh[3] = (__bf16)v.w; ll[3] = (__bf16)(v.w - (float)hh[3]);
    *(bf16x4*)(xh + i) = hh;
    *(bf16x4*)(xl + i) = ll;
}

// ---- split-bf16 MFMA GEMM, m97-style: global_load_lds(16B) async staging into
// double-buffered subtiled LDS [buf][plane][kslot][128 rows][8 elems]; 2-phase
// pipeline (prefetch t+1 before compute t; one vmcnt(0)+barrier per K-step).
// Subtiled layout => fragment ds_read_b128 = consecutive 16B per lane group
// (conflict-free) and results bit-identical to the reg-staged version.
__global__ __launch_bounds__(256) void gemm_mfma(
    const __bf16* __restrict__ Ah, const __bf16* __restrict__ Al,
    const __bf16* __restrict__ Bth, const __bf16* __restrict__ Btl,
    const float* __restrict__ bias, const float* __restrict__ residual,
    float* __restrict__ C, __bf16* __restrict__ CbH, __bf16* __restrict__ CbL,
    int nrows, int do_relu) {
    // planes: 0=Ah 1=Al 2=Bh 3=Bl ; 2*4*4*128*8*2B = 64 KB
    __shared__ __attribute__((aligned(16))) __bf16 sm[2][4][4][128][8];

    int row0 = blockIdx.x * 128;
    int n0   = blockIdx.y * 128;
    int tid  = threadIdx.x;
    int lane = tid & 63, wave = tid >> 6;
    int wm = (wave >> 1) * 64, wn = (wave & 1) * 64;

    f32x4 acc[4][4];
    #pragma unroll
    for (int i = 0; i < 4; i++)
        #pragma unroll
        for (int j = 0; j < 4; j++) acc[i][j] = (f32x4)(0.f);

    // staging decomposition: thread t covers row (t&127), k-slots {shi, 2+shi}
    int srow = tid & 127;
    int shi  = tid >> 7;
    const __bf16* gA0 = Ah  + (size_t)(row0 + srow) * 256;  // rows < RP (padded)
    const __bf16* gA1 = Al  + (size_t)(row0 + srow) * 256;
    const __bf16* gB0 = Bth + (size_t)(n0 + srow) * 256;
    const __bf16* gB1 = Btl + (size_t)(n0 + srow) * 256;
    char* lds0 = (char*)&sm[0][0][0][0][0];

    // 8 async 16B DMAs; lds byte (buf*4+plane)*8192 + j*4096 + tid*16
    // == plane base + slot*2048 + row*16 with slot = j*2+shi, row = t&127.
#define STAGE(buf, kk) do {                                                   \
        int ke0 = (kk) + shi * 8;                                             \
        int ke1 = (kk) + (2 + shi) * 8;                                       \
        size_t lo0 = (size_t)(buf) * 32768 + (size_t)tid * 16;                \
        size_t lo1 = lo0 + 4096;                                              \
        gload16(gA0 + ke0, lds0 + lo0);                                       \
        gload16(gA0 + ke1, lds0 + lo1);                                       \
        gload16(gA1 + ke0, lds0 + 8192 + lo0);                                \
        gload16(gA1 + ke1, lds0 + 8192 + lo1);                                \
        gload16(gB0 + ke0, lds0 + 16384 + lo0);                               \
        gload16(gB0 + ke1, lds0 + 16384 + lo1);                               \
        gload16(gB1 + ke0, lds0 + 24576 + lo0);                               \
        gload16(gB1 + ke1, lds0 + 24576 + lo1);                               \
    } while (0)

    STAGE(0, 0);
    __syncthreads();   // drains vmcnt(0): buffer 0 ready

    int h = lane >> 4;               // k-slot of this lane's fragment
    int m_base = wm + (lane & 15);
    int n_base = wn + (lane & 15);

    for (int t = 0; t < 8; t++) {
        int cur = t & 1;
        if (t < 7) STAGE(cur ^ 1, (t + 1) * 32);   // prefetch next K-step

        bf16x8 ahf[4], alf[4], bhf[4], blf[4];
        #pragma unroll
        for (int mt = 0; mt < 4; mt++) {
            ahf[mt] = *(const bf16x8*)&sm[cur][0][h][m_base + mt * 16][0];
            alf[mt] = *(const bf16x8*)&sm[cur][1][h][m_base + mt * 16][0];
        }
        #pragma unroll
        for (int nt = 0; nt < 4; nt++) {
            bhf[nt] = *(const bf16x8*)&sm[cur][2][h][n_base + nt * 16][0];
            blf[nt] = *(const bf16x8*)&sm[cur][3][h][n_base + nt * 16][0];
        }
        #pragma unroll
        for (int mt = 0; mt < 4; mt++)
            #pragma unroll
            for (int nt = 0; nt < 4; nt++) {
                acc[mt][nt] = __builtin_amdgcn_mfma_f32_16x16x32_bf16(ahf[mt], bhf[nt], acc[mt][nt], 0, 0, 0);
                acc[mt][nt] = __builtin_amdgcn_mfma_f32_16x16x32_bf16(alf[mt], bhf[nt], acc[mt][nt], 0, 0, 0);
                acc[mt][nt] = __builtin_amdgcn_mfma_f32_16x16x32_bf16(ahf[mt], blf[nt], acc[mt][nt], 0, 0, 0);
            }
        __syncthreads();   // one vmcnt(0)+barrier per step; prefetch hid under MFMA
    }
#undef STAGE

    #pragma unroll
    for (int mt = 0; mt < 4; mt++) {
        #pragma unroll
        for (int nt = 0; nt < 4; nt++) {
            int col = n0 + wn + nt * 16 + (lane & 15);
            #pragma unroll
            for (int rr = 0; rr < 4; rr++) {
                int row = row0 + wm + mt * 16 + (lane >> 4) * 4 + rr;
                if (row < nrows) {
                    float v = acc[mt][nt][rr] + bias[col];
                    if (do_relu) v = fmaxf(v, 0.f);
                    size_t idx = (size_t)row * 256 + col;
                    if (CbH) {
                        __bf16 hh = (__bf16)v;
                        CbH[idx] = hh;
                        if (CbL) CbL[idx] = (__bf16)(v - (float)hh);
                    } else {
                        if (residual) v += residual[idx];
                        C[idx] = v;
                    }
                }
            }
        }
    }
}

// ---- CSR build ----
__global__ void hist_kernel(const int* __restrict__ recv, int* __restrict__ counts) {
    int t = blockIdx.x * 256 + threadIdx.x;
    if (t < M_EDGES) atomicAdd(&counts[recv[t]], 1);
}

__global__ void scan_kernel(const int* __restrict__ counts, int* __restrict__ offsets) {
    __shared__ int part[256];
    int t = threadIdx.x;
    const int per = (N_NODES + 255) / 256;
    int start = t * per;
    int end = min(start + per, N_NODES);
    int s = 0;
    for (int i = start; i < end; i++) s += counts[i];
    part[t] = s;
    __syncthreads();
    if (t == 0) {
        int acc = 0;
        for (int i = 0; i < 256; i++) { int v = part[i]; part[i] = acc; acc += v; }
    }
    __syncthreads();
    int acc = part[t];
    for (int i = start; i < end; i++) { offsets[i] = acc; acc += counts[i]; }
    if (end == N_NODES && start < N_NODES) offsets[N_NODES] = acc;
}

__global__ void fill_kernel(const int* __restrict__ recv, const int* __restrict__ send,
                            const int* __restrict__ offsets,
                            int* __restrict__ cursor, int* __restrict__ ssorted,
                            int* __restrict__ rsorted) {
    int t = blockIdx.x * 256 + threadIdx.x;
    if (t < M_EDGES) {
        int r = recv[t];
        int pos = offsets[r] + atomicAdd(&cursor[r], 1);
        ssorted[pos] = send[t];
        rsorted[pos] = r;
    }
}

// ---- edge logits. GRID-STRIDE sliding window (all waves stay inside one
// ~16K-edge window -> instantaneous Q working set ~1MB, L2-shared) with
// 4 independent slots per wave-iteration for memory-level parallelism.
// [best measured form: 120.4 us @ 1024 blocks]
__global__ __launch_bounds__(256) void qk_csr_kernel(
    const int* __restrict__ ssorted, const int* __restrict__ rsorted,
    const float* __restrict__ Q, const unsigned short* __restrict__ Kb,
    float* __restrict__ qks, unsigned* __restrict__ gmax) {
    int wave_id = (blockIdx.x * 256 + threadIdx.x) >> 6;
    int lane = threadIdx.x & 63;
    int e_slot = lane >> 5;        // which edge of the pair
    int sl = lane & 31;            // 16B chunk within row
    const int nwaves = (gridDim.x * 256) >> 6;
    const int npairs = M_EDGES / 2;
    float wmax = -INFINITY;
    for (int pp = wave_id; pp < npairs; pp += 4 * nwaves) {
        int ep[4]; bool valid[4];
        #pragma unroll
        for (int u = 0; u < 4; u++) {
            int p = pp + u * nwaves;
            valid[u] = p < npairs;
            ep[u] = (valid[u] ? p : pp) * 2 + e_slot;
        }
        // batch all index loads, then all row gathers -> 4 independent chains
        int si[4], ri[4];
        #pragma unroll
        for (int u = 0; u < 4; u++) { si[u] = ssorted[ep[u]]; ri[u] = rsorted[ep[u]]; }
        uint4 kv[4]; float4 qa[4], qb[4];
        #pragma unroll
        for (int u = 0; u < 4; u++) {
            kv[u] = *(const uint4*)(Kb + (size_t)si[u] * 256 + sl * 8);
            qa[u] = *(const float4*)(Q + (size_t)ri[u] * 256 + sl * 8);
            qb[u] = *(const float4*)(Q + (size_t)ri[u] * 256 + sl * 8 + 4);
        }
        #pragma unroll
        for (int u = 0; u < 4; u++) {
            float d = qa[u].x * bflo(kv[u].x) + qa[u].y * bfhi(kv[u].x)
                    + qa[u].z * bflo(kv[u].y) + qa[u].w * bfhi(kv[u].y)
                    + qb[u].x * bflo(kv[u].z) + qb[u].y * bfhi(kv[u].z)
                    + qb[u].z * bflo(kv[u].w) + qb[u].w * bfhi(kv[u].w);
            d += __shfl_xor(d, 1);
            d += __shfl_xor(d, 2);
            wmax = fmaxf(wmax, d);
            if ((sl & 3) == 0 && valid[u])
                qks[(size_t)ep[u] * 8 + (sl >> 2)] = d;
        }
    }
    // wave max reduce + one atomic per wave
    wmax = fmaxf(wmax, __shfl_xor(wmax, 1));
    wmax = fmaxf(wmax, __shfl_xor(wmax, 2));
    wmax = fmaxf(wmax, __shfl_xor(wmax, 4));
    wmax = fmaxf(wmax, __shfl_xor(wmax, 8));
    wmax = fmaxf(wmax, __shfl_xor(wmax, 16));
    wmax = fmaxf(wmax, __shfl_xor(wmax, 32));
    if (lane == 0 && wmax > -INFINITY) atomicMax(gmax, enc_ord(wmax));
}

// ---- node aggregation: one wave per node (64 lanes x 4 cols = 256), CONTIGUOUS
// per-wave node chunks. Emits msg directly as SPLIT bf16 (h+l planes) for the
// Wagg GEMM's async staging (bit-identical values).
__global__ __launch_bounds__(256) void node_agg_kernel(
    const int* __restrict__ offsets, const int* __restrict__ ssorted,
    const float* __restrict__ qks, const unsigned short* __restrict__ Vb,
    const unsigned* __restrict__ gmax,
    __bf16* __restrict__ msgH, __bf16* __restrict__ msgL) {
    int wave_id = (blockIdx.x * 256 + threadIdx.x) >> 6;
    int lane = threadIdx.x & 63;   // columns lane*4 .. lane*4+3
    int h = lane >> 3;             // head of these columns
    const int nwaves = (gridDim.x * 256) >> 6;
    const int per = (N_NODES + nwaves - 1) / nwaves;
    int n0 = wave_id * per;
    int nend = min(n0 + per, N_NODES);
    float scale = 3.0f / dec_ord(*gmax);
    for (int n = n0; n < nend; n++) {
        int off = offsets[n];
        int deg = offsets[n + 1] - off;
        float sum = 0.f, a0 = 0.f, a1 = 0.f, a2 = 0.f, a3 = 0.f;
        for (int b = 0; b < deg; b += 64) {
            int bn = min(64, deg - b);
            int idxb = ssorted[off + b + min(lane, bn - 1)];  // coalesced index batch
            #define VROW(i) (*(const uint2*)(Vb + \
                (size_t)__shfl(idxb, min((i), bn - 1)) * 256 + lane * 4))
            #define QKL(i) qks[(size_t)(off + b + min((i), bn - 1)) * 8 + h]
            uint2 v0 = VROW(0);
            uint2 v1 = VROW(1);
            float q0 = QKL(0);
            float q1 = QKL(1);
            for (int i = 0; i < bn; i++) {
                uint2 vc = v0; v0 = v1; v1 = VROW(i + 2);
                float qc = q0; q0 = q1; q1 = QKL(i + 2);
                float a = __expf(qc * scale);
                sum += a;
                a0 += a * bflo(vc.x); a1 += a * bfhi(vc.x);
                a2 += a * bflo(vc.y); a3 += a * bfhi(vc.y);
            }
            #undef VROW
            #undef QKL
        }
        float inv = (deg > 0) ? 1.0f / (sum * 5.65685424949238f) : 0.f;  // sqrt(32)
        float r0 = fmaxf(a0 * inv, 0.f), r1 = fmaxf(a1 * inv, 0.f);
        float r2 = fmaxf(a2 * inv, 0.f), r3 = fmaxf(a3 * inv, 0.f);
        bf16x4 hv, lv;
        hv[0] = (__bf16)r0; lv[0] = (__bf16)(r0 - (float)hv[0]);
        hv[1] = (__bf16)r1; lv[1] = (__bf16)(r1 - (float)hv[1]);
        hv[2] = (__bf16)r2; lv[2] = (__bf16)(r2 - (float)hv[2]);
        hv[3] = (__bf16)r3; lv[3] = (__bf16)(r3 - (float)hv[3]);
        *(bf16x4*)(msgH + (size_t)n * 256 + lane * 4) = hv;
        *(bf16x4*)(msgL + (size_t)n * 256 + lane * 4) = lv;
    }
}

extern "C" void kernel_launch(void* const* d_in, const int* in_sizes, int n_in,
                              void* d_out, int out_size, void* d_ws, size_t ws_size,
                              hipStream_t stream) {
    const float* x    = (const float*)d_in[0];
    const int*   edge = (const int*)d_in[1];
    const int*   recv = edge;
    const int*   send = edge + M_EDGES;
    const float* Wk   = (const float*)d_in[2];
    const float* bk   = (const float*)d_in[3];
    const float* Wq   = (const float*)d_in[4];
    const float* bq   = (const float*)d_in[5];
    const float* Wv   = (const float*)d_in[6];
    const float* bv   = (const float*)d_in[7];
    const float* Wagg = (const float*)d_in[8];
    const float* bagg = (const float*)d_in[9];
    const float* Wff  = (const float*)d_in[10];
    const float* bff  = (const float*)d_in[11];
    float* out = (float*)d_out;

    float*  Qbuf  = (float*)d_ws;                       // RP*256 f32
    float*  reg2  = Qbuf + (size_t)RP * 256;            // RP*256 f32 multi-use region
    float*  qks   = reg2 + (size_t)RP * 256;
    __bf16* Kbf   = (__bf16*)(qks + (size_t)M_EDGES * 8);
    __bf16* Vbf   = Kbf + (size_t)RP * 256;
    int* counts   = (int*)(Vbf + (size_t)RP * 256);
    int* cursor   = counts + N_NODES;
    int* offsets  = cursor + N_NODES;
    int* ssorted  = offsets + N_NODES + 1;
    unsigned* gmax = (unsigned*)(ssorted + M_EDGES);
    __bf16* wt    = (__bf16*)(gmax + 1);
    __bf16* WkH = wt;              __bf16* WkL = wt + 65536;
    __bf16* WqH = wt + 2 * 65536;  __bf16* WqL = wt + 3 * 65536;
    __bf16* WvH = wt + 4 * 65536;  __bf16* WvL = wt + 5 * 65536;
    __bf16* WaH = wt + 6 * 65536;  __bf16* WaL = wt + 7 * 65536;
    __bf16* WfH = wt + 8 * 65536;  __bf16* WfL = wt + 9 * 65536;
    // reg2 overlays (strictly sequenced):
    //   xsplit..V-gemm : xh/xl (split x)
    //   fill..qk       : rsorted
    //   node_agg..Wagg : msgH/msgL
    __bf16* xh   = (__bf16*)reg2;
    __bf16* xl   = xh + (size_t)RP * 256;
    int*    rsorted = (int*)reg2;
    __bf16* msgH = (__bf16*)reg2;
    __bf16* msgL = msgH + (size_t)RP * 256;
    // Qbuf overlay: hidden split planes (Q dead after qk_csr_kernel)
    __bf16* hidH = (__bf16*)Qbuf;
    __bf16* hidL = hidH + (size_t)RP * 256;

    dim3 blk(256);
    dim3 gemm_grid((N_NODES + 127) / 128, 2);
    dim3 edge_grid((M_EDGES + 255) / 256);

    hipLaunchKernelGGL(init_kernel, dim3((N_NODES + 255) / 256), blk, 0, stream,
                       counts, cursor, gmax);
    hipLaunchKernelGGL(wsplit_kernel, dim3(256), blk, 0, stream, Wk,   WkH, WkL);
    hipLaunchKernelGGL(wsplit_kernel, dim3(256), blk, 0, stream, Wq,   WqH, WqL);
    hipLaunchKernelGGL(wsplit_kernel, dim3(256), blk, 0, stream, Wv,   WvH, WvL);
    hipLaunchKernelGGL(wsplit_kernel, dim3(256), blk, 0, stream, Wagg, WaH, WaL);
    hipLaunchKernelGGL(wsplit_kernel, dim3(256), blk, 0, stream, Wff,  WfH, WfL);
    // split x once (enables async bf16 staging in all GEMMs)
    hipLaunchKernelGGL(xsplit_kernel, dim3((N_NODES * 256 / 4 + 255) / 256), blk, 0,
                       stream, x, xh, xl);
    // projections (MFMA, async-staged); K,V emitted as bf16, Q fp32
    hipLaunchKernelGGL(gemm_mfma, gemm_grid, blk, 0, stream, xh, xl, WkH, WkL, bk,
                       nullptr, (float*)nullptr, Kbf, (__bf16*)nullptr, N_NODES, 0);
    hipLaunchKernelGGL(gemm_mfma, gemm_grid, blk, 0, stream, xh, xl, WqH, WqL, bq,
                       nullptr, Qbuf, (__bf16*)nullptr, (__bf16*)nullptr, N_NODES, 0);
    hipLaunchKernelGGL(gemm_mfma, gemm_grid, blk, 0, stream, xh, xl, WvH, WvL, bv,
                       nullptr, (float*)nullptr, Vbf, (__bf16*)nullptr, N_NODES, 0);
    // CSR build (rsorted overlays reg2: xh/xl dead after V gemm)
    hipLaunchKernelGGL(hist_kernel, edge_grid, blk, 0, stream, recv, counts);
    hipLaunchKernelGGL(scan_kernel, dim3(1), blk, 0, stream, counts, offsets);
    hipLaunchKernelGGL(fill_kernel, edge_grid, blk, 0, stream, recv, send, offsets,
                       cursor, ssorted, rsorted);
    // edge logits + global max (persistent, sliding-window grid-stride, 4-slot ILP)
    hipLaunchKernelGGL(qk_csr_kernel, dim3(1024), blk, 0, stream,
                       ssorted, rsorted, Qbuf, (const unsigned short*)Kbf, qks, gmax);
    // segment softmax + aggregate -> split-bf16 msg (overwrites rsorted region)
    hipLaunchKernelGGL(node_agg_kernel, dim3(2048), blk, 0, stream,
                       offsets, ssorted, qks, (const unsigned short*)Vbf, gmax,
                       msgH, msgL);
    // output MLP (MFMA): Wagg -> split-bf16 hidden (overlays Qbuf), Wff -> out
    hipLaunchKernelGGL(gemm_mfma, gemm_grid, blk, 0, stream, msgH, msgL, WaH, WaL,
                       bagg, nullptr, (float*)nullptr, hidH, hidL, N_NODES, 1);
    hipLaunchKernelGGL(gemm_mfma, gemm_grid, blk, 0, stream, hidH, hidL, WfH, WfL,
                       bff, x, out, (__bf16*)nullptr, (__bf16*)nullptr, N_NODES, 1);
}

// Round 6
// 833.515 us; speedup vs baseline: 1.0529x; 1.0529x over previous
//
#include <hip/hip_runtime.h>

#define N_NODES 50000
#define M_EDGES 800000
#define RP 50048  // padded row count for matrix buffers

typedef __bf16 bf16x8 __attribute__((ext_vector_type(8)));
typedef __bf16 bf16x4 __attribute__((ext_vector_type(4)));
typedef float  f32x4  __attribute__((ext_vector_type(4)));

static __device__ __forceinline__ unsigned enc_ord(float f) {
    unsigned b = __float_as_uint(f);
    return (b & 0x80000000u) ? ~b : (b | 0x80000000u);
}
static __device__ __forceinline__ float dec_ord(unsigned u) {
    unsigned b = (u & 0x80000000u) ? (u ^ 0x80000000u) : ~u;
    return __uint_as_float(b);
}
// bf16 pair packed in a uint: lo = bits[15:0], hi = bits[31:16]
static __device__ __forceinline__ float bflo(unsigned u) { return __uint_as_float(u << 16); }
static __device__ __forceinline__ float bfhi(unsigned u) { return __uint_as_float(u & 0xffff0000u); }

// async 16B global -> LDS DMA (vmcnt op; LDS dest = wave-uniform base + lane*16)
static __device__ __forceinline__ void gload16(const void* g, void* l) {
    __builtin_amdgcn_global_load_lds(
        (const __attribute__((address_space(1))) void*)g,
        (__attribute__((address_space(3))) void*)l, 16, 0, 0);
}

// ---- ONE prep dispatch: 5 weight splits (Wk/Wq/Wv fused into [768][256] planes,
// Wagg/Wff separate), x split, bias concat, counts/cursor/gmax zero.
__global__ __launch_bounds__(256) void prep_kernel(
    const float* __restrict__ Wk, const float* __restrict__ Wq,
    const float* __restrict__ Wv, const float* __restrict__ Wagg,
    const float* __restrict__ Wff,
    const float* __restrict__ bk, const float* __restrict__ bq,
    const float* __restrict__ bv,
    const float* __restrict__ X,
    __bf16* __restrict__ WHq, __bf16* __restrict__ WLq,
    __bf16* __restrict__ WaH, __bf16* __restrict__ WaL,
    __bf16* __restrict__ WfH, __bf16* __restrict__ WfL,
    float* __restrict__ bqkv, __bf16* __restrict__ xh, __bf16* __restrict__ xl,
    int* __restrict__ counts, int* __restrict__ cursor, unsigned* __restrict__ gmax) {
    int gid = blockIdx.x * 256 + threadIdx.x;
    int stride = gridDim.x * 256;
    // weights: B^T layout, row = output col, col = k
    for (int i = gid; i < 65536; i += stride) {
        int n = i >> 8, k = i & 255;
        size_t src = (size_t)k * 256 + n;
        float v; __bf16 h;
        v = Wk[src];   h = (__bf16)v; WHq[(size_t)n * 256 + k] = h;
                       WLq[(size_t)n * 256 + k] = (__bf16)(v - (float)h);
        v = Wq[src];   h = (__bf16)v; WHq[(size_t)(256 + n) * 256 + k] = h;
                       WLq[(size_t)(256 + n) * 256 + k] = (__bf16)(v - (float)h);
        v = Wv[src];   h = (__bf16)v; WHq[(size_t)(512 + n) * 256 + k] = h;
                       WLq[(size_t)(512 + n) * 256 + k] = (__bf16)(v - (float)h);
        v = Wagg[src]; h = (__bf16)v; WaH[i] = h; WaL[i] = (__bf16)(v - (float)h);
        v = Wff[src];  h = (__bf16)v; WfH[i] = h; WfL[i] = (__bf16)(v - (float)h);
    }
    // x split (float4 granularity)
    const size_t nx = (size_t)N_NODES * 256 / 4;
    for (size_t i = gid; i < nx; i += stride) {
        float4 v = *(const float4*)(X + i * 4);
        bf16x4 hh, ll;
        hh[0] = (__bf16)v.x; ll[0] = (__bf16)(v.x - (float)hh[0]);
        hh[1] = (__bf16)v.y; ll[1] = (__bf16)(v.y - (float)hh[1]);
        hh[2] = (__bf16)v.z; ll[2] = (__bf16)(v.z - (float)hh[2]);
        hh[3] = (__bf16)v.w; ll[3] = (__bf16)(v.w - (float)hh[3]);
        *(bf16x4*)(xh + i * 4) = hh;
        *(bf16x4*)(xl + i * 4) = ll;
    }
    for (int i = gid; i < 768; i += stride)
        bqkv[i] = (i < 256) ? bk[i] : ((i < 512) ? bq[i - 256] : bv[i - 512]);
    for (int i = gid; i < N_NODES; i += stride) { counts[i] = 0; cursor[i] = 0; }
    if (gid == 0) *gmax = 0u;
}

// ---- FUSED K|Q|V projection GEMM: one dispatch, grid (391, 6), B = [768][256]
// fused split planes. Epilogue routes output col range: [0,256)->Kbf bf16,
// [256,512)->Qbuf f32, [512,768)->Vbf bf16. Math identical to 3 separate GEMMs.
__global__ __launch_bounds__(256) void gemm_qkv(
    const __bf16* __restrict__ Ah, const __bf16* __restrict__ Al,
    const __bf16* __restrict__ Bth, const __bf16* __restrict__ Btl,
    const float* __restrict__ bqkv,
    __bf16* __restrict__ Kb, float* __restrict__ Qo, __bf16* __restrict__ Vb) {
    __shared__ __attribute__((aligned(16))) __bf16 sm[2][4][4][128][8];

    int row0 = blockIdx.x * 128;
    int n0   = blockIdx.y * 128;   // 0..640, fused output col base
    int tid  = threadIdx.x;
    int lane = tid & 63, wave = tid >> 6;
    int wm = (wave >> 1) * 64, wn = (wave & 1) * 64;

    f32x4 acc[4][4];
    #pragma unroll
    for (int i = 0; i < 4; i++)
        #pragma unroll
        for (int j = 0; j < 4; j++) acc[i][j] = (f32x4)(0.f);

    int srow = tid & 127;
    int shi  = tid >> 7;
    const __bf16* gA0 = Ah  + (size_t)(row0 + srow) * 256;
    const __bf16* gA1 = Al  + (size_t)(row0 + srow) * 256;
    const __bf16* gB0 = Bth + (size_t)(n0 + srow) * 256;
    const __bf16* gB1 = Btl + (size_t)(n0 + srow) * 256;
    char* lds0 = (char*)&sm[0][0][0][0][0];

#define STAGE(buf, kk) do {                                                   \
        int ke0 = (kk) + shi * 8;                                             \
        int ke1 = (kk) + (2 + shi) * 8;                                       \
        size_t lo0 = (size_t)(buf) * 32768 + (size_t)tid * 16;                \
        size_t lo1 = lo0 + 4096;                                              \
        gload16(gA0 + ke0, lds0 + lo0);                                       \
        gload16(gA0 + ke1, lds0 + lo1);                                       \
        gload16(gA1 + ke0, lds0 + 8192 + lo0);                                \
        gload16(gA1 + ke1, lds0 + 8192 + lo1);                                \
        gload16(gB0 + ke0, lds0 + 16384 + lo0);                               \
        gload16(gB0 + ke1, lds0 + 16384 + lo1);                               \
        gload16(gB1 + ke0, lds0 + 24576 + lo0);                               \
        gload16(gB1 + ke1, lds0 + 24576 + lo1);                               \
    } while (0)

    STAGE(0, 0);
    __syncthreads();

    int h = lane >> 4;
    int m_base = wm + (lane & 15);
    int n_base = wn + (lane & 15);

    for (int t = 0; t < 8; t++) {
        int cur = t & 1;
        if (t < 7) STAGE(cur ^ 1, (t + 1) * 32);
        bf16x8 ahf[4], alf[4], bhf[4], blf[4];
        #pragma unroll
        for (int mt = 0; mt < 4; mt++) {
            ahf[mt] = *(const bf16x8*)&sm[cur][0][h][m_base + mt * 16][0];
            alf[mt] = *(const bf16x8*)&sm[cur][1][h][m_base + mt * 16][0];
        }
        #pragma unroll
        for (int nt = 0; nt < 4; nt++) {
            bhf[nt] = *(const bf16x8*)&sm[cur][2][h][n_base + nt * 16][0];
            blf[nt] = *(const bf16x8*)&sm[cur][3][h][n_base + nt * 16][0];
        }
        #pragma unroll
        for (int mt = 0; mt < 4; mt++)
            #pragma unroll
            for (int nt = 0; nt < 4; nt++) {
                acc[mt][nt] = __builtin_amdgcn_mfma_f32_16x16x32_bf16(ahf[mt], bhf[nt], acc[mt][nt], 0, 0, 0);
                acc[mt][nt] = __builtin_amdgcn_mfma_f32_16x16x32_bf16(alf[mt], bhf[nt], acc[mt][nt], 0, 0, 0);
                acc[mt][nt] = __builtin_amdgcn_mfma_f32_16x16x32_bf16(ahf[mt], blf[nt], acc[mt][nt], 0, 0, 0);
            }
        __syncthreads();
    }

    #pragma unroll
    for (int mt = 0; mt < 4; mt++) {
        #pragma unroll
        for (int nt = 0; nt < 4; nt++) {
            int cg = n0 + wn + nt * 16 + (lane & 15);   // fused col 0..767
            #pragma unroll
            for (int rr = 0; rr < 4; rr++) {
                int row = row0 + wm + mt * 16 + (lane >> 4) * 4 + rr;
                if (row < N_NODES) {
                    float v = acc[mt][nt][rr] + bqkv[cg];
                    if (cg < 256)      Kb[(size_t)row * 256 + cg] = (__bf16)v;
                    else if (cg < 512) Qo[(size_t)row * 256 + (cg - 256)] = v;
                    else               Vb[(size_t)row * 256 + (cg - 512)] = (__bf16)v;
                }
            }
        }
    }
}

// ---- generic split-bf16 MFMA GEMM (async DMA, double-buffered) — used for
// Wagg/Wff; kept IDENTICAL to round-5 as in-run control dispatches.
__global__ __launch_bounds__(256) void gemm_mfma(
    const __bf16* __restrict__ Ah, const __bf16* __restrict__ Al,
    const __bf16* __restrict__ Bth, const __bf16* __restrict__ Btl,
    const float* __restrict__ bias, const float* __restrict__ residual,
    float* __restrict__ C, __bf16* __restrict__ CbH, __bf16* __restrict__ CbL,
    int nrows, int do_relu) {
    __shared__ __attribute__((aligned(16))) __bf16 sm[2][4][4][128][8];

    int row0 = blockIdx.x * 128;
    int n0   = blockIdx.y * 128;
    int tid  = threadIdx.x;
    int lane = tid & 63, wave = tid >> 6;
    int wm = (wave >> 1) * 64, wn = (wave & 1) * 64;

    f32x4 acc[4][4];
    #pragma unroll
    for (int i = 0; i < 4; i++)
        #pragma unroll
        for (int j = 0; j < 4; j++) acc[i][j] = (f32x4)(0.f);

    int srow = tid & 127;
    int shi  = tid >> 7;
    const __bf16* gA0 = Ah  + (size_t)(row0 + srow) * 256;
    const __bf16* gA1 = Al  + (size_t)(row0 + srow) * 256;
    const __bf16* gB0 = Bth + (size_t)(n0 + srow) * 256;
    const __bf16* gB1 = Btl + (size_t)(n0 + srow) * 256;
    char* lds0 = (char*)&sm[0][0][0][0][0];

    STAGE(0, 0);
    __syncthreads();

    int h = lane >> 4;
    int m_base = wm + (lane & 15);
    int n_base = wn + (lane & 15);

    for (int t = 0; t < 8; t++) {
        int cur = t & 1;
        if (t < 7) STAGE(cur ^ 1, (t + 1) * 32);
        bf16x8 ahf[4], alf[4], bhf[4], blf[4];
        #pragma unroll
        for (int mt = 0; mt < 4; mt++) {
            ahf[mt] = *(const bf16x8*)&sm[cur][0][h][m_base + mt * 16][0];
            alf[mt] = *(const bf16x8*)&sm[cur][1][h][m_base + mt * 16][0];
        }
        #pragma unroll
        for (int nt = 0; nt < 4; nt++) {
            bhf[nt] = *(const bf16x8*)&sm[cur][2][h][n_base + nt * 16][0];
            blf[nt] = *(const bf16x8*)&sm[cur][3][h][n_base + nt * 16][0];
        }
        #pragma unroll
        for (int mt = 0; mt < 4; mt++)
            #pragma unroll
            for (int nt = 0; nt < 4; nt++) {
                acc[mt][nt] = __builtin_amdgcn_mfma_f32_16x16x32_bf16(ahf[mt], bhf[nt], acc[mt][nt], 0, 0, 0);
                acc[mt][nt] = __builtin_amdgcn_mfma_f32_16x16x32_bf16(alf[mt], bhf[nt], acc[mt][nt], 0, 0, 0);
                acc[mt][nt] = __builtin_amdgcn_mfma_f32_16x16x32_bf16(ahf[mt], blf[nt], acc[mt][nt], 0, 0, 0);
            }
        __syncthreads();
    }
#undef STAGE

    #pragma unroll
    for (int mt = 0; mt < 4; mt++) {
        #pragma unroll
        for (int nt = 0; nt < 4; nt++) {
            int col = n0 + wn + nt * 16 + (lane & 15);
            #pragma unroll
            for (int rr = 0; rr < 4; rr++) {
                int row = row0 + wm + mt * 16 + (lane >> 4) * 4 + rr;
                if (row < nrows) {
                    float v = acc[mt][nt][rr] + bias[col];
                    if (do_relu) v = fmaxf(v, 0.f);
                    size_t idx = (size_t)row * 256 + col;
                    if (CbH) {
                        __bf16 hh = (__bf16)v;
                        CbH[idx] = hh;
                        if (CbL) CbL[idx] = (__bf16)(v - (float)hh);
                    } else {
                        if (residual) v += residual[idx];
                        C[idx] = v;
                    }
                }
            }
        }
    }
}

// ---- CSR build ----
__global__ void hist_kernel(const int* __restrict__ recv, int* __restrict__ counts) {
    int t = blockIdx.x * 256 + threadIdx.x;
    if (t < M_EDGES) atomicAdd(&counts[recv[t]], 1);
}

__global__ void scan_kernel(const int* __restrict__ counts, int* __restrict__ offsets) {
    __shared__ int part[256];
    int t = threadIdx.x;
    const int per = (N_NODES + 255) / 256;
    int start = t * per;
    int end = min(start + per, N_NODES);
    int s = 0;
    for (int i = start; i < end; i++) s += counts[i];
    part[t] = s;
    __syncthreads();
    if (t == 0) {
        int acc = 0;
        for (int i = 0; i < 256; i++) { int v = part[i]; part[i] = acc; acc += v; }
    }
    __syncthreads();
    int acc = part[t];
    for (int i = start; i < end; i++) { offsets[i] = acc; acc += counts[i]; }
    if (end == N_NODES && start < N_NODES) offsets[N_NODES] = acc;
}

__global__ void fill_kernel(const int* __restrict__ recv, const int* __restrict__ send,
                            const int* __restrict__ offsets,
                            int* __restrict__ cursor, int* __restrict__ ssorted,
                            int* __restrict__ rsorted) {
    int t = blockIdx.x * 256 + threadIdx.x;
    if (t < M_EDGES) {
        int r = recv[t];
        int pos = offsets[r] + atomicAdd(&cursor[r], 1);
        ssorted[pos] = send[t];
        rsorted[pos] = r;
    }
}

// ---- edge logits. GRID-STRIDE sliding window, 4-slot ILP.
// [best measured form: 120.4 us @ 1024 blocks]
__global__ __launch_bounds__(256) void qk_csr_kernel(
    const int* __restrict__ ssorted, const int* __restrict__ rsorted,
    const float* __restrict__ Q, const unsigned short* __restrict__ Kb,
    float* __restrict__ qks, unsigned* __restrict__ gmax) {
    int wave_id = (blockIdx.x * 256 + threadIdx.x) >> 6;
    int lane = threadIdx.x & 63;
    int e_slot = lane >> 5;        // which edge of the pair
    int sl = lane & 31;            // 16B chunk within row
    const int nwaves = (gridDim.x * 256) >> 6;
    const int npairs = M_EDGES / 2;
    float wmax = -INFINITY;
    for (int pp = wave_id; pp < npairs; pp += 4 * nwaves) {
        int ep[4]; bool valid[4];
        #pragma unroll
        for (int u = 0; u < 4; u++) {
            int p = pp + u * nwaves;
            valid[u] = p < npairs;
            ep[u] = (valid[u] ? p : pp) * 2 + e_slot;
        }
        int si[4], ri[4];
        #pragma unroll
        for (int u = 0; u < 4; u++) { si[u] = ssorted[ep[u]]; ri[u] = rsorted[ep[u]]; }
        uint4 kv[4]; float4 qa[4], qb[4];
        #pragma unroll
        for (int u = 0; u < 4; u++) {
            kv[u] = *(const uint4*)(Kb + (size_t)si[u] * 256 + sl * 8);
            qa[u] = *(const float4*)(Q + (size_t)ri[u] * 256 + sl * 8);
            qb[u] = *(const float4*)(Q + (size_t)ri[u] * 256 + sl * 8 + 4);
        }
        #pragma unroll
        for (int u = 0; u < 4; u++) {
            float d = qa[u].x * bflo(kv[u].x) + qa[u].y * bfhi(kv[u].x)
                    + qa[u].z * bflo(kv[u].y) + qa[u].w * bfhi(kv[u].y)
                    + qb[u].x * bflo(kv[u].z) + qb[u].y * bfhi(kv[u].z)
                    + qb[u].z * bflo(kv[u].w) + qb[u].w * bfhi(kv[u].w);
            d += __shfl_xor(d, 1);
            d += __shfl_xor(d, 2);
            wmax = fmaxf(wmax, d);
            if ((sl & 3) == 0 && valid[u])
                qks[(size_t)ep[u] * 8 + (sl >> 2)] = d;
        }
    }
    wmax = fmaxf(wmax, __shfl_xor(wmax, 1));
    wmax = fmaxf(wmax, __shfl_xor(wmax, 2));
    wmax = fmaxf(wmax, __shfl_xor(wmax, 4));
    wmax = fmaxf(wmax, __shfl_xor(wmax, 8));
    wmax = fmaxf(wmax, __shfl_xor(wmax, 16));
    wmax = fmaxf(wmax, __shfl_xor(wmax, 32));
    if (lane == 0 && wmax > -INFINITY) atomicMax(gmax, enc_ord(wmax));
}

// ---- node aggregation (wave-per-node, contiguous chunks, split-bf16 msg out)
__global__ __launch_bounds__(256) void node_agg_kernel(
    const int* __restrict__ offsets, const int* __restrict__ ssorted,
    const float* __restrict__ qks, const unsigned short* __restrict__ Vb,
    const unsigned* __restrict__ gmax,
    __bf16* __restrict__ msgH, __bf16* __restrict__ msgL) {
    int wave_id = (blockIdx.x * 256 + threadIdx.x) >> 6;
    int lane = threadIdx.x & 63;   // columns lane*4 .. lane*4+3
    int h = lane >> 3;             // head of these columns
    const int nwaves = (gridDim.x * 256) >> 6;
    const int per = (N_NODES + nwaves - 1) / nwaves;
    int n0 = wave_id * per;
    int nend = min(n0 + per, N_NODES);
    float scale = 3.0f / dec_ord(*gmax);
    for (int n = n0; n < nend; n++) {
        int off = offsets[n];
        int deg = offsets[n + 1] - off;
        float sum = 0.f, a0 = 0.f, a1 = 0.f, a2 = 0.f, a3 = 0.f;
        for (int b = 0; b < deg; b += 64) {
            int bn = min(64, deg - b);
            int idxb = ssorted[off + b + min(lane, bn - 1)];
            #define VROW(i) (*(const uint2*)(Vb + \
                (size_t)__shfl(idxb, min((i), bn - 1)) * 256 + lane * 4))
            #define QKL(i) qks[(size_t)(off + b + min((i), bn - 1)) * 8 + h]
            uint2 v0 = VROW(0);
            uint2 v1 = VROW(1);
            float q0 = QKL(0);
            float q1 = QKL(1);
            for (int i = 0; i < bn; i++) {
                uint2 vc = v0; v0 = v1; v1 = VROW(i + 2);
                float qc = q0; q0 = q1; q1 = QKL(i + 2);
                float a = __expf(qc * scale);
                sum += a;
                a0 += a * bflo(vc.x); a1 += a * bfhi(vc.x);
                a2 += a * bflo(vc.y); a3 += a * bfhi(vc.y);
            }
            #undef VROW
            #undef QKL
        }
        float inv = (deg > 0) ? 1.0f / (sum * 5.65685424949238f) : 0.f;  // sqrt(32)
        float r0 = fmaxf(a0 * inv, 0.f), r1 = fmaxf(a1 * inv, 0.f);
        float r2 = fmaxf(a2 * inv, 0.f), r3 = fmaxf(a3 * inv, 0.f);
        bf16x4 hv, lv;
        hv[0] = (__bf16)r0; lv[0] = (__bf16)(r0 - (float)hv[0]);
        hv[1] = (__bf16)r1; lv[1] = (__bf16)(r1 - (float)hv[1]);
        hv[2] = (__bf16)r2; lv[2] = (__bf16)(r2 - (float)hv[2]);
        hv[3] = (__bf16)r3; lv[3] = (__bf16)(r3 - (float)hv[3]);
        *(bf16x4*)(msgH + (size_t)n * 256 + lane * 4) = hv;
        *(bf16x4*)(msgL + (size_t)n * 256 + lane * 4) = lv;
    }
}

extern "C" void kernel_launch(void* const* d_in, const int* in_sizes, int n_in,
                              void* d_out, int out_size, void* d_ws, size_t ws_size,
                              hipStream_t stream) {
    const float* x    = (const float*)d_in[0];
    const int*   edge = (const int*)d_in[1];
    const int*   recv = edge;
    const int*   send = edge + M_EDGES;
    const float* Wk   = (const float*)d_in[2];
    const float* bk   = (const float*)d_in[3];
    const float* Wq   = (const float*)d_in[4];
    const float* bq   = (const float*)d_in[5];
    const float* Wv   = (const float*)d_in[6];
    const float* bv   = (const float*)d_in[7];
    const float* Wagg = (const float*)d_in[8];
    const float* bagg = (const float*)d_in[9];
    const float* Wff  = (const float*)d_in[10];
    const float* bff  = (const float*)d_in[11];
    float* out = (float*)d_out;

    float*  Qbuf  = (float*)d_ws;                       // RP*256 f32
    float*  reg2  = Qbuf + (size_t)RP * 256;            // RP*256 f32 multi-use region
    float*  qks   = reg2 + (size_t)RP * 256;
    __bf16* Kbf   = (__bf16*)(qks + (size_t)M_EDGES * 8);
    __bf16* Vbf   = Kbf + (size_t)RP * 256;
    int* counts   = (int*)(Vbf + (size_t)RP * 256);
    int* cursor   = counts + N_NODES;
    int* offsets  = cursor + N_NODES;
    int* ssorted  = offsets + N_NODES + 1;
    unsigned* gmax = (unsigned*)(ssorted + M_EDGES);
    __bf16* wt    = (__bf16*)(gmax + 1);
    __bf16* WHq = wt;                    // [768][256]
    __bf16* WLq = wt + 3 * 65536;        // [768][256]
    __bf16* WaH = wt + 6 * 65536;  __bf16* WaL = wt + 7 * 65536;
    __bf16* WfH = wt + 8 * 65536;  __bf16* WfL = wt + 9 * 65536;
    float* bqkv = (float*)(wt + 10 * 65536);   // [768]
    // reg2 overlays (strictly sequenced):
    //   prep..qkv-gemm : xh/xl (split x)
    //   fill..qk       : rsorted
    //   node_agg..Wagg : msgH/msgL
    __bf16* xh   = (__bf16*)reg2;
    __bf16* xl   = xh + (size_t)RP * 256;
    int*    rsorted = (int*)reg2;
    __bf16* msgH = (__bf16*)reg2;
    __bf16* msgL = msgH + (size_t)RP * 256;
    // Qbuf overlay: hidden split planes (Q dead after qk_csr_kernel)
    __bf16* hidH = (__bf16*)Qbuf;
    __bf16* hidL = hidH + (size_t)RP * 256;

    dim3 blk(256);
    dim3 qkv_grid((N_NODES + 127) / 128, 6);
    dim3 gemm_grid((N_NODES + 127) / 128, 2);
    dim3 edge_grid((M_EDGES + 255) / 256);

    // ONE prep dispatch (weights, x split, bias concat, zeroing)
    hipLaunchKernelGGL(prep_kernel, dim3(2048), blk, 0, stream,
                       Wk, Wq, Wv, Wagg, Wff, bk, bq, bv, x,
                       WHq, WLq, WaH, WaL, WfH, WfL, bqkv, xh, xl,
                       counts, cursor, gmax);
    // ONE fused K|Q|V projection GEMM
    hipLaunchKernelGGL(gemm_qkv, qkv_grid, blk, 0, stream,
                       xh, xl, WHq, WLq, bqkv, Kbf, Qbuf, Vbf);
    // CSR build (rsorted overlays reg2: xh/xl dead after QKV gemm)
    hipLaunchKernelGGL(hist_kernel, edge_grid, blk, 0, stream, recv, counts);
    hipLaunchKernelGGL(scan_kernel, dim3(1), blk, 0, stream, counts, offsets);
    hipLaunchKernelGGL(fill_kernel, edge_grid, blk, 0, stream, recv, send, offsets,
                       cursor, ssorted, rsorted);
    // edge logits + global max
    hipLaunchKernelGGL(qk_csr_kernel, dim3(1024), blk, 0, stream,
                       ssorted, rsorted, Qbuf, (const unsigned short*)Kbf, qks, gmax);
    // segment softmax + aggregate -> split-bf16 msg
    hipLaunchKernelGGL(node_agg_kernel, dim3(2048), blk, 0, stream,
                       offsets, ssorted, qks, (const unsigned short*)Vbf, gmax,
                       msgH, msgL);
    // output MLP (controls: unchanged geometry)
    hipLaunchKernelGGL(gemm_mfma, gemm_grid, blk, 0, stream, msgH, msgL, WaH, WaL,
                       bagg, nullptr, (float*)nullptr, hidH, hidL, N_NODES, 1);
    hipLaunchKernelGGL(gemm_mfma, gemm_grid, blk, 0, stream, hidH, hidL, WfH, WfL,
                       bff, x, out, (__bf16*)nullptr, (__bf16*)nullptr, N_NODES, 1);
}